// Round 2
// baseline (18195.920 us; speedup 1.0000x reference)
//
#include <hip/hip_runtime.h>
#include <math.h>

#define S_LEN 64
#define T_LEN 64
#define BSZ   32
#define EDIM  512
#define HDIM  1024
#define VDIM  32000
#define FOURH 4096

typedef __attribute__((ext_vector_type(8))) short  short8;
typedef __attribute__((ext_vector_type(4))) float  floatx4;

__device__ __forceinline__ unsigned short f2bf(float x){
  unsigned u = __float_as_uint(x);
  u = (u + 0x7FFFu + ((u >> 16) & 1u)) >> 16;
  return (unsigned short)u;
}
__device__ __forceinline__ float sigm(float x){ return 1.f/(1.f+__expf(-x)); }

// ---------------- fp32 -> bf16 conversion (vectorized, grid-stride) ----------------
__global__ void cvt_bf16_v4(const float* __restrict__ in, unsigned short* __restrict__ out, long n4){
  long i = (long)blockIdx.x*blockDim.x + threadIdx.x;
  long stride = (long)gridDim.x*blockDim.x;
  for (; i < n4; i += stride){
    float4 v = ((const float4*)in)[i];
    ushort4 o; o.x=f2bf(v.x); o.y=f2bf(v.y); o.z=f2bf(v.z); o.w=f2bf(v.w);
    ((ushort4*)out)[i] = o;
  }
}

// ---------------- embedding gather -> bf16 rows [rows][EDIM] ----------------
__global__ void embed_gather(const int* __restrict__ toks, const float* __restrict__ emb,
                             unsigned short* __restrict__ out, int total4){
  int i = blockIdx.x*blockDim.x + threadIdx.x;
  if (i >= total4) return;
  const int e4 = EDIM/4;
  int r = i / e4, e = (i % e4)*4;
  int tok = toks[r];
  float4 v = *(const float4*)(emb + (size_t)tok*EDIM + e);
  ushort4 o; o.x=f2bf(v.x); o.y=f2bf(v.y); o.z=f2bf(v.z); o.w=f2bf(v.w);
  *(ushort4*)(out + (size_t)r*EDIM + e) = o;
}

// ---------------- target token per projection row ----------------
__global__ void tok_row_kernel(const int* __restrict__ tgt, int* __restrict__ tokRow){
  int r = blockIdx.x*blockDim.x + threadIdx.x;
  if (r >= T_LEN*BSZ) return;
  int t = r >> 5, b = r & 31;
  tokRow[r] = (t < T_LEN-1) ? tgt[(t+1)*BSZ + b] : -1;
}

// ---------------- bf16 MFMA GEMM: C[M,N] = A[M,K] * W[N,K]^T (+bias) ----------------
// EPI==0: store C (fp32) + bias.  EPI==1: fused exp-sum + target-logit epilogue.
template<int EPI>
__global__ __launch_bounds__(256,1) void gemm_mfma(
    const unsigned short* __restrict__ A, int lda,
    const unsigned short* __restrict__ W, int ldw,
    const float* __restrict__ bias,
    float* __restrict__ C, int ldc, int K,
    float* __restrict__ rowSum, float* __restrict__ logitTgt, const int* __restrict__ tokRow)
{
  __shared__ unsigned short As[128*32];
  __shared__ unsigned short Ws[128*32];
  const int tid  = threadIdx.x;
  const int wave = tid >> 6, lane = tid & 63;
  const int bm = blockIdx.x * 128, bn = blockIdx.y * 128;
  const int wr = (wave >> 1) * 64, wc = (wave & 1) * 64;
  const int srow = tid >> 2, scol = (tid & 3) * 8;
  const int rg = (lane >> 4) * 8, rl = lane & 15;
  floatx4 acc[4][4] = {};

  for (int kt = 0; kt < K; kt += 32){
    short8 a0 = *(const short8*)(A + (size_t)(bm + srow)*lda      + kt + scol);
    short8 a1 = *(const short8*)(A + (size_t)(bm + 64 + srow)*lda + kt + scol);
    short8 w0 = *(const short8*)(W + (size_t)(bn + srow)*ldw      + kt + scol);
    short8 w1 = *(const short8*)(W + (size_t)(bn + 64 + srow)*ldw + kt + scol);
    __syncthreads();
    *(short8*)&As[srow*32 + scol]      = a0;
    *(short8*)&As[(64+srow)*32 + scol] = a1;
    *(short8*)&Ws[srow*32 + scol]      = w0;
    *(short8*)&Ws[(64+srow)*32 + scol] = w1;
    __syncthreads();
    short8 af[4], wf[4];
    #pragma unroll
    for (int m=0;m<4;m++) af[m] = *(const short8*)&As[(wr + m*16 + rl)*32 + rg];
    #pragma unroll
    for (int n=0;n<4;n++) wf[n] = *(const short8*)&Ws[(wc + n*16 + rl)*32 + rg];
    #pragma unroll
    for (int m=0;m<4;m++)
      #pragma unroll
      for (int n=0;n<4;n++)
        acc[m][n] = __builtin_amdgcn_mfma_f32_16x16x32_bf16(af[m], wf[n], acc[m][n], 0, 0, 0);
  }

  if (EPI == 0){
    float bv[4];
    #pragma unroll
    for (int n=0;n<4;n++) bv[n] = bias[bn + wc + n*16 + rl];
    #pragma unroll
    for (int m=0;m<4;m++){
      #pragma unroll
      for (int j=0;j<4;j++){
        int r = bm + wr + m*16 + (lane>>4)*4 + j;
        #pragma unroll
        for (int n=0;n<4;n++){
          int c = bn + wc + n*16 + rl;
          C[(size_t)r*ldc + c] = acc[m][n][j] + bv[n];
        }
      }
    }
  } else {
    #pragma unroll
    for (int m=0;m<4;m++){
      #pragma unroll
      for (int j=0;j<4;j++){
        int r = bm + wr + m*16 + (lane>>4)*4 + j;
        int tok = tokRow[r];
        float esum = 0.f;
        #pragma unroll
        for (int n=0;n<4;n++){
          int c = bn + wc + n*16 + rl;
          float v = acc[m][n][j];
          if (c == tok) logitTgt[r] = v;
          esum += __expf(v);
        }
        esum += __shfl_xor(esum, 1);
        esum += __shfl_xor(esum, 2);
        esum += __shfl_xor(esum, 4);
        esum += __shfl_xor(esum, 8);
        if (rl == 0) atomicAdd(&rowSum[r], esum);
      }
    }
  }
}

// ---------------- encoder layer-0 step: z0 = preZ + h0*Whh^T -> cell -> tmp ----------------
__global__ __launch_bounds__(256,1) void enc_l0_kernel(
    const float* __restrict__ preZ, const float* __restrict__ Whh,
    const float* __restrict__ h0, const float* __restrict__ c0,
    float* __restrict__ h0t, float* __restrict__ c0t, int t)
{
  const int wave = threadIdx.x >> 6, lane = threadIdx.x & 63;
  const int i = blockIdx.x*4 + wave;
  const int kb = lane*16;
  float4 wv[4][4];
  #pragma unroll
  for (int g=0; g<4; g++){
    const float* wrow = Whh + (size_t)(g*HDIM + i)*HDIM + kb;
    #pragma unroll
    for (int q=0;q<4;q++) wv[g][q] = *(const float4*)(wrow + q*4);
  }
  for (int b=0; b<BSZ; b++){
    const float* hp = h0 + b*HDIM + kb;
    float4 hv[4];
    #pragma unroll
    for (int q=0;q<4;q++) hv[q] = *(const float4*)(hp + q*4);
    float s0=0,s1=0,s2=0,s3=0;
    #pragma unroll
    for (int q=0;q<4;q++){
      s0 += wv[0][q].x*hv[q].x + wv[0][q].y*hv[q].y + wv[0][q].z*hv[q].z + wv[0][q].w*hv[q].w;
      s1 += wv[1][q].x*hv[q].x + wv[1][q].y*hv[q].y + wv[1][q].z*hv[q].z + wv[1][q].w*hv[q].w;
      s2 += wv[2][q].x*hv[q].x + wv[2][q].y*hv[q].y + wv[2][q].z*hv[q].z + wv[2][q].w*hv[q].w;
      s3 += wv[3][q].x*hv[q].x + wv[3][q].y*hv[q].y + wv[3][q].z*hv[q].z + wv[3][q].w*hv[q].w;
    }
    #pragma unroll
    for (int off=1; off<64; off<<=1){
      s0 += __shfl_xor(s0, off); s1 += __shfl_xor(s1, off);
      s2 += __shfl_xor(s2, off); s3 += __shfl_xor(s3, off);
    }
    if (lane == 0){
      const float* pz = preZ + (size_t)(t*BSZ + b)*FOURH;
      float zi = pz[i] + s0, zf = pz[HDIM+i] + s1, zg = pz[2*HDIM+i] + s2, zo = pz[3*HDIM+i] + s3;
      float cc = sigm(zf)*c0[b*HDIM+i] + sigm(zi)*tanhf(zg);
      float hh = sigm(zo)*tanhf(cc);
      h0t[b*HDIM+i] = hh; c0t[b*HDIM+i] = cc;
    }
  }
}

// ---------------- encoder layer-1 step + packed-seq masking + state commit ----------------
__global__ __launch_bounds__(256,1) void enc_l1_kernel(
    const float* __restrict__ Wih, const float* __restrict__ Whh, const float* __restrict__ bias,
    const float* __restrict__ h0t, const float* __restrict__ c0t,
    const float* __restrict__ h1, const float* __restrict__ c1,
    const float* __restrict__ h0p, const float* __restrict__ c0p,
    float* __restrict__ h0n, float* __restrict__ c0n,
    float* __restrict__ h1n, float* __restrict__ c1n,
    float* __restrict__ ench, const int* __restrict__ elen, int t)
{
  const int wave = threadIdx.x >> 6, lane = threadIdx.x & 63;
  const int i = blockIdx.x*4 + wave;
  const int kb = lane*16;
  float4 wi[4][4], wh[4][4];
  #pragma unroll
  for (int g=0; g<4; g++){
    const float* r1 = Wih + (size_t)(g*HDIM + i)*HDIM + kb;
    const float* r2 = Whh + (size_t)(g*HDIM + i)*HDIM + kb;
    #pragma unroll
    for (int q=0;q<4;q++){ wi[g][q] = *(const float4*)(r1 + q*4); wh[g][q] = *(const float4*)(r2 + q*4); }
  }
  float bz0 = bias[i], bz1 = bias[HDIM+i], bz2 = bias[2*HDIM+i], bz3 = bias[3*HDIM+i];
  for (int b=0; b<BSZ; b++){
    const float* xp = h0t + b*HDIM + kb;
    const float* hp = h1  + b*HDIM + kb;
    float4 xv[4], hv[4];
    #pragma unroll
    for (int q=0;q<4;q++){ xv[q] = *(const float4*)(xp + q*4); hv[q] = *(const float4*)(hp + q*4); }
    float s0=0,s1=0,s2=0,s3=0;
    #pragma unroll
    for (int q=0;q<4;q++){
      s0 += wi[0][q].x*xv[q].x + wi[0][q].y*xv[q].y + wi[0][q].z*xv[q].z + wi[0][q].w*xv[q].w
          + wh[0][q].x*hv[q].x + wh[0][q].y*hv[q].y + wh[0][q].z*hv[q].z + wh[0][q].w*hv[q].w;
      s1 += wi[1][q].x*xv[q].x + wi[1][q].y*xv[q].y + wi[1][q].z*xv[q].z + wi[1][q].w*xv[q].w
          + wh[1][q].x*hv[q].x + wh[1][q].y*hv[q].y + wh[1][q].z*hv[q].z + wh[1][q].w*hv[q].w;
      s2 += wi[2][q].x*xv[q].x + wi[2][q].y*xv[q].y + wi[2][q].z*xv[q].z + wi[2][q].w*xv[q].w
          + wh[2][q].x*hv[q].x + wh[2][q].y*hv[q].y + wh[2][q].z*hv[q].z + wh[2][q].w*hv[q].w;
      s3 += wi[3][q].x*xv[q].x + wi[3][q].y*xv[q].y + wi[3][q].z*xv[q].z + wi[3][q].w*xv[q].w
          + wh[3][q].x*hv[q].x + wh[3][q].y*hv[q].y + wh[3][q].z*hv[q].z + wh[3][q].w*hv[q].w;
    }
    #pragma unroll
    for (int off=1; off<64; off<<=1){
      s0 += __shfl_xor(s0, off); s1 += __shfl_xor(s1, off);
      s2 += __shfl_xor(s2, off); s3 += __shfl_xor(s3, off);
    }
    if (lane == 0){
      float zi = bz0+s0, zf = bz1+s1, zg = bz2+s2, zo = bz3+s3;
      float cc = sigm(zf)*c1[b*HDIM+i] + sigm(zi)*tanhf(zg);
      float hh = sigm(zo)*tanhf(cc);
      bool valid = t < elen[b];
      size_t bi = (size_t)b*HDIM + i;
      if (valid){
        h0n[bi] = h0t[bi]; c0n[bi] = c0t[bi]; h1n[bi] = hh; c1n[bi] = cc;
        ench[((size_t)t*BSZ + b)*HDIM + i] = hh;
      } else {
        h0n[bi] = h0p[bi]; c0n[bi] = c0p[bi]; h1n[bi] = h1[bi]; c1n[bi] = c1[bi];
        ench[((size_t)t*BSZ + b)*HDIM + i] = 0.f;
      }
    }
  }
}

// ---------------- decoder layer-0 step: z0 = preZ + ht*Wih[:,E:]^T + hd0*Whh^T ----------------
__global__ __launch_bounds__(256,1) void dec_l0_kernel(
    const float* __restrict__ preZ, const float* __restrict__ Wih, const float* __restrict__ Whh,
    const float* __restrict__ ht, const float* __restrict__ hd0, const float* __restrict__ cd0,
    float* __restrict__ h0t, float* __restrict__ c0t, int t)
{
  const int wave = threadIdx.x >> 6, lane = threadIdx.x & 63;
  const int i = blockIdx.x*4 + wave;
  const int kb = lane*16;
  float4 wi[4][4], wh[4][4];
  #pragma unroll
  for (int g=0; g<4; g++){
    const float* r1 = Wih + (size_t)(g*HDIM + i)*(EDIM+HDIM) + EDIM + kb;
    const float* r2 = Whh + (size_t)(g*HDIM + i)*HDIM + kb;
    #pragma unroll
    for (int q=0;q<4;q++){ wi[g][q] = *(const float4*)(r1 + q*4); wh[g][q] = *(const float4*)(r2 + q*4); }
  }
  for (int b=0; b<BSZ; b++){
    const float* xp = ht  + b*HDIM + kb;
    const float* hp = hd0 + b*HDIM + kb;
    float4 xv[4], hv[4];
    #pragma unroll
    for (int q=0;q<4;q++){ xv[q] = *(const float4*)(xp + q*4); hv[q] = *(const float4*)(hp + q*4); }
    float s0=0,s1=0,s2=0,s3=0;
    #pragma unroll
    for (int q=0;q<4;q++){
      s0 += wi[0][q].x*xv[q].x + wi[0][q].y*xv[q].y + wi[0][q].z*xv[q].z + wi[0][q].w*xv[q].w
          + wh[0][q].x*hv[q].x + wh[0][q].y*hv[q].y + wh[0][q].z*hv[q].z + wh[0][q].w*hv[q].w;
      s1 += wi[1][q].x*xv[q].x + wi[1][q].y*xv[q].y + wi[1][q].z*xv[q].z + wi[1][q].w*xv[q].w
          + wh[1][q].x*hv[q].x + wh[1][q].y*hv[q].y + wh[1][q].z*hv[q].z + wh[1][q].w*hv[q].w;
      s2 += wi[2][q].x*xv[q].x + wi[2][q].y*xv[q].y + wi[2][q].z*xv[q].z + wi[2][q].w*xv[q].w
          + wh[2][q].x*hv[q].x + wh[2][q].y*hv[q].y + wh[2][q].z*hv[q].z + wh[2][q].w*hv[q].w;
      s3 += wi[3][q].x*xv[q].x + wi[3][q].y*xv[q].y + wi[3][q].z*xv[q].z + wi[3][q].w*xv[q].w
          + wh[3][q].x*hv[q].x + wh[3][q].y*hv[q].y + wh[3][q].z*hv[q].z + wh[3][q].w*hv[q].w;
    }
    #pragma unroll
    for (int off=1; off<64; off<<=1){
      s0 += __shfl_xor(s0, off); s1 += __shfl_xor(s1, off);
      s2 += __shfl_xor(s2, off); s3 += __shfl_xor(s3, off);
    }
    if (lane == 0){
      const float* pz = preZ + (size_t)(t*BSZ + b)*FOURH;
      float zi = pz[i]+s0, zf = pz[HDIM+i]+s1, zg = pz[2*HDIM+i]+s2, zo = pz[3*HDIM+i]+s3;
      float cc = sigm(zf)*cd0[b*HDIM+i] + sigm(zi)*tanhf(zg);
      float hh = sigm(zo)*tanhf(cc);
      h0t[b*HDIM+i] = hh; c0t[b*HDIM+i] = cc;
    }
  }
}

// ---------------- decoder layer-1 step + state commit + yt ----------------
__global__ __launch_bounds__(256,1) void dec_l1_kernel(
    const float* __restrict__ Wih, const float* __restrict__ Whh, const float* __restrict__ bias,
    const float* __restrict__ h0t, const float* __restrict__ c0t,
    const float* __restrict__ h1, const float* __restrict__ c1,
    float* __restrict__ h0n, float* __restrict__ c0n,
    float* __restrict__ h1n, float* __restrict__ c1n,
    float* __restrict__ yt)
{
  const int wave = threadIdx.x >> 6, lane = threadIdx.x & 63;
  const int i = blockIdx.x*4 + wave;
  const int kb = lane*16;
  float4 wi[4][4], wh[4][4];
  #pragma unroll
  for (int g=0; g<4; g++){
    const float* r1 = Wih + (size_t)(g*HDIM + i)*HDIM + kb;
    const float* r2 = Whh + (size_t)(g*HDIM + i)*HDIM + kb;
    #pragma unroll
    for (int q=0;q<4;q++){ wi[g][q] = *(const float4*)(r1 + q*4); wh[g][q] = *(const float4*)(r2 + q*4); }
  }
  float bz0 = bias[i], bz1 = bias[HDIM+i], bz2 = bias[2*HDIM+i], bz3 = bias[3*HDIM+i];
  for (int b=0; b<BSZ; b++){
    const float* xp = h0t + b*HDIM + kb;
    const float* hp = h1  + b*HDIM + kb;
    float4 xv[4], hv[4];
    #pragma unroll
    for (int q=0;q<4;q++){ xv[q] = *(const float4*)(xp + q*4); hv[q] = *(const float4*)(hp + q*4); }
    float s0=0,s1=0,s2=0,s3=0;
    #pragma unroll
    for (int q=0;q<4;q++){
      s0 += wi[0][q].x*xv[q].x + wi[0][q].y*xv[q].y + wi[0][q].z*xv[q].z + wi[0][q].w*xv[q].w
          + wh[0][q].x*hv[q].x + wh[0][q].y*hv[q].y + wh[0][q].z*hv[q].z + wh[0][q].w*hv[q].w;
      s1 += wi[1][q].x*xv[q].x + wi[1][q].y*xv[q].y + wi[1][q].z*xv[q].z + wi[1][q].w*xv[q].w
          + wh[1][q].x*hv[q].x + wh[1][q].y*hv[q].y + wh[1][q].z*hv[q].z + wh[1][q].w*hv[q].w;
      s2 += wi[2][q].x*xv[q].x + wi[2][q].y*xv[q].y + wi[2][q].z*xv[q].z + wi[2][q].w*xv[q].w
          + wh[2][q].x*hv[q].x + wh[2][q].y*hv[q].y + wh[2][q].z*hv[q].z + wh[2][q].w*hv[q].w;
      s3 += wi[3][q].x*xv[q].x + wi[3][q].y*xv[q].y + wi[3][q].z*xv[q].z + wi[3][q].w*xv[q].w
          + wh[3][q].x*hv[q].x + wh[3][q].y*hv[q].y + wh[3][q].z*hv[q].z + wh[3][q].w*hv[q].w;
    }
    #pragma unroll
    for (int off=1; off<64; off<<=1){
      s0 += __shfl_xor(s0, off); s1 += __shfl_xor(s1, off);
      s2 += __shfl_xor(s2, off); s3 += __shfl_xor(s3, off);
    }
    if (lane == 0){
      float zi = bz0+s0, zf = bz1+s1, zg = bz2+s2, zo = bz3+s3;
      float cc = sigm(zf)*c1[b*HDIM+i] + sigm(zi)*tanhf(zg);
      float hh = sigm(zo)*tanhf(cc);
      size_t bi = (size_t)b*HDIM + i;
      h0n[bi] = h0t[bi]; c0n[bi] = c0t[bi]; h1n[bi] = hh; c1n[bi] = cc;
      yt[bi] = hh;
    }
  }
}

// ---------------- attention part A: tanv = tanh(yt*Wht^T), scores[b,s] ----------------
__global__ __launch_bounds__(256,1) void dec_attn_a(
    const float* __restrict__ Wht, const float* __restrict__ yt, const float* __restrict__ ench,
    float* __restrict__ tanv, float* __restrict__ scores)
{
  const int wave = threadIdx.x >> 6, lane = threadIdx.x & 63;
  const int wid = blockIdx.x*4 + wave;
  const int kb = lane*16;
  if (wid < HDIM){
    const int i = wid;
    float4 wv[4];
    #pragma unroll
    for (int q=0;q<4;q++) wv[q] = *(const float4*)(Wht + (size_t)i*HDIM + kb + q*4);
    for (int b=0; b<BSZ; b++){
      const float* hp = yt + b*HDIM + kb;
      float s = 0;
      #pragma unroll
      for (int q=0;q<4;q++){
        float4 hv = *(const float4*)(hp + q*4);
        s += wv[q].x*hv.x + wv[q].y*hv.y + wv[q].z*hv.z + wv[q].w*hv.w;
      }
      #pragma unroll
      for (int off=1; off<64; off<<=1) s += __shfl_xor(s, off);
      if (lane == 0) tanv[b*HDIM + i] = tanhf(s);
    }
  } else {
    const int sid = wid - HDIM;
    const int b = sid >> 6, s_idx = sid & 63;
    const float* yp = yt + b*HDIM + kb;
    const float* ep = ench + ((size_t)s_idx*BSZ + b)*HDIM + kb;
    float s = 0;
    #pragma unroll
    for (int q=0;q<4;q++){
      float4 yv = *(const float4*)(yp + q*4);
      float4 ev = *(const float4*)(ep + q*4);
      s += yv.x*ev.x + yv.y*ev.y + yv.z*ev.z + yv.w*ev.w;
    }
    #pragma unroll
    for (int off=1; off<64; off<<=1) s += __shfl_xor(s, off);
    if (lane == 0) scores[b*S_LEN + s_idx] = s;
  }
}

// ---------------- attention part B: pt, softmax+window -> at, ct ----------------
__global__ __launch_bounds__(256,1) void dec_attn_b(
    const float* __restrict__ tanv, const float* __restrict__ w_tan2pt,
    const float* __restrict__ scores, const int* __restrict__ elen,
    const float* __restrict__ ench, float* __restrict__ ct)
{
  const int b = blockIdx.x, tid = threadIdx.x;
  __shared__ float red[256];
  __shared__ float atS[S_LEN];
  __shared__ float ptS;
  float part = 0;
  for (int k = tid; k < HDIM; k += 256) part += tanv[b*HDIM + k]*w_tan2pt[k];
  red[tid] = part; __syncthreads();
  for (int off = 128; off; off >>= 1){ if (tid < off) red[tid] += red[tid+off]; __syncthreads(); }
  if (tid == 0) ptS = sigm(red[0]) * (float)elen[b];
  __syncthreads();
  if (tid < 64){
    int L = elen[b];
    float sc = (tid < L) ? scores[b*S_LEN + tid] : -1e30f;
    float m = sc;
    #pragma unroll
    for (int off=1; off<64; off<<=1) m = fmaxf(m, __shfl_xor(m, off));
    float e = (tid < L) ? __expf(sc - m) : 0.f;
    float ssum = e;
    #pragma unroll
    for (int off=1; off<64; off<<=1) ssum += __shfl_xor(ssum, off);
    float d = (float)tid - ptS;
    atS[tid] = (e/ssum) * __expf(-(d*d)*(1.0f/50.0f));  // WIN_D^2/2 = 50
  }
  __syncthreads();
  const int h0 = tid*4;
  float4 acc = {0,0,0,0};
  for (int s = 0; s < S_LEN; s++){
    float a = atS[s];
    float4 v = *(const float4*)(ench + ((size_t)s*BSZ + b)*HDIM + h0);
    acc.x += a*v.x; acc.y += a*v.y; acc.z += a*v.z; acc.w += a*v.w;
  }
  *(float4*)(ct + b*HDIM + h0) = acc;
}

// ---------------- attention part C: ht = tanh(cat(ct,yt)*Wct^T) ----------------
__global__ __launch_bounds__(256,1) void dec_attn_c(
    const float* __restrict__ Wct, const float* __restrict__ ct, const float* __restrict__ yt,
    float* __restrict__ htn, unsigned short* __restrict__ decoutb, int t)
{
  const int wave = threadIdx.x >> 6, lane = threadIdx.x & 63;
  const int i = blockIdx.x*4 + wave;
  float4 wv[8];
  #pragma unroll
  for (int q=0;q<8;q++) wv[q] = *(const float4*)(Wct + (size_t)i*(2*HDIM) + lane*32 + q*4);
  const float* xsrc = (lane < 32) ? ct : yt;
  const int col = (lane & 31) * 32;
  for (int b=0; b<BSZ; b++){
    const float* xp = xsrc + b*HDIM + col;
    float s = 0;
    #pragma unroll
    for (int q=0;q<8;q++){
      float4 xv = *(const float4*)(xp + q*4);
      s += wv[q].x*xv.x + wv[q].y*xv.y + wv[q].z*xv.z + wv[q].w*xv.w;
    }
    #pragma unroll
    for (int off=1; off<64; off<<=1) s += __shfl_xor(s, off);
    if (lane == 0){
      float v = tanhf(s);
      htn[(size_t)b*HDIM + i] = v;
      decoutb[((size_t)t*BSZ + b)*HDIM + i] = f2bf(v);
    }
  }
}

// ---------------- final loss: out[b] = sum_t mask*(logitTgt - log(rowSum)) ----------------
__global__ void loss_kernel(const float* __restrict__ rowSum, const float* __restrict__ logitTgt,
                            const int* __restrict__ tgt, float* __restrict__ out)
{
  const int b = blockIdx.x, t = threadIdx.x;  // 64 threads
  float v = 0.f;
  if (t < T_LEN-1){
    int r = t*BSZ + b;
    if (tgt[(t+1)*BSZ + b] != 0) v = logitTgt[r] - logf(rowSum[r]);
  }
  #pragma unroll
  for (int off=1; off<64; off<<=1) v += __shfl_xor(v, off);
  if (t == 0) out[b] = v;
}

// =====================================================================================
extern "C" void kernel_launch(void* const* d_in, const int* in_sizes, int n_in,
                              void* d_out, int out_size, void* d_ws, size_t ws_size,
                              hipStream_t stream)
{
  const int*   src_tokens = (const int*)d_in[0];
  const int*   tgt_tokens = (const int*)d_in[1];
  const int*   encode_len = (const int*)d_in[2];
  const float* emb_src  = (const float*)d_in[3];
  const float* emb_tar  = (const float*)d_in[4];
  const float* eW_ih0   = (const float*)d_in[5];
  const float* eW_hh0   = (const float*)d_in[6];
  const float* eb0      = (const float*)d_in[7];
  const float* eW_ih1   = (const float*)d_in[8];
  const float* eW_hh1   = (const float*)d_in[9];
  const float* eb1      = (const float*)d_in[10];
  const float* dW_ih0   = (const float*)d_in[11];
  const float* dW_hh0   = (const float*)d_in[12];
  const float* db0      = (const float*)d_in[13];
  const float* dW_ih1   = (const float*)d_in[14];
  const float* dW_hh1   = (const float*)d_in[15];
  const float* db1      = (const float*)d_in[16];
  const float* W_ht2tan = (const float*)d_in[17];
  const float* w_tan2pt = (const float*)d_in[18];
  const float* W_ct2ht  = (const float*)d_in[19];
  const float* W_final  = (const float*)d_in[20];
  float* out = (float*)d_out;

  char* wsp = (char*)d_ws;
  auto alloc = [&](size_t bytes)->void*{
    void* p = (void*)wsp; wsp += ((bytes + 255) & ~(size_t)255); return p;
  };
  float* preZe = (float*)alloc(2048ull*4096*4);
  float* preZd = (float*)alloc(2048ull*4096*4);
  float* ench  = (float*)alloc((size_t)S_LEN*BSZ*HDIM*4);
  float* h0s   = (float*)alloc(2ull*BSZ*HDIM*4);
  float* c0s   = (float*)alloc(2ull*BSZ*HDIM*4);
  float* h1s   = (float*)alloc(2ull*BSZ*HDIM*4);
  float* c1s   = (float*)alloc(2ull*BSZ*HDIM*4);
  float* hts   = (float*)alloc(2ull*BSZ*HDIM*4);
  float* h0t   = (float*)alloc((size_t)BSZ*HDIM*4);
  float* c0t   = (float*)alloc((size_t)BSZ*HDIM*4);
  float* ytb   = (float*)alloc((size_t)BSZ*HDIM*4);
  float* tanv  = (float*)alloc((size_t)BSZ*HDIM*4);
  float* ctb   = (float*)alloc((size_t)BSZ*HDIM*4);
  float* scores= (float*)alloc((size_t)BSZ*S_LEN*4);
  float* rowSum   = (float*)alloc(2048*4);
  float* logitTgt = (float*)alloc(2048*4);
  int*   tokRow   = (int*)alloc(2048*4);
  unsigned short* xsrc    = (unsigned short*)alloc(2048ull*EDIM*2);
  unsigned short* ytgt    = (unsigned short*)alloc(2048ull*EDIM*2);
  unsigned short* eWih0b  = (unsigned short*)alloc((size_t)FOURH*EDIM*2);
  unsigned short* dWih0b  = (unsigned short*)alloc((size_t)FOURH*(EDIM+HDIM)*2);
  unsigned short* Wfinb   = (unsigned short*)alloc((size_t)VDIM*HDIM*2);
  unsigned short* decoutb = (unsigned short*)alloc(2048ull*HDIM*2);

  const size_t ST = (size_t)BSZ*HDIM;  // 32768 floats per state

  // zero-init parity-0 states, ht, rowSum
  hipMemsetAsync(h0s, 0, ST*4, stream);
  hipMemsetAsync(c0s, 0, ST*4, stream);
  hipMemsetAsync(h1s, 0, ST*4, stream);
  hipMemsetAsync(c1s, 0, ST*4, stream);
  hipMemsetAsync(hts, 0, ST*4, stream);
  hipMemsetAsync(rowSum, 0, 2048*4, stream);

  // weight conversions + embedding gathers
  cvt_bf16_v4<<<1024, 256, 0, stream>>>(eW_ih0, eWih0b, (long)FOURH*EDIM/4);
  cvt_bf16_v4<<<2048, 256, 0, stream>>>(dW_ih0, dWih0b, (long)FOURH*(EDIM+HDIM)/4);
  cvt_bf16_v4<<<4096, 256, 0, stream>>>(W_final, Wfinb, (long)VDIM*HDIM/4);
  embed_gather<<<(2048*EDIM/4 + 255)/256, 256, 0, stream>>>(src_tokens, emb_src, xsrc, 2048*EDIM/4);
  embed_gather<<<(2048*EDIM/4 + 255)/256, 256, 0, stream>>>(tgt_tokens, emb_tar, ytgt, 2048*EDIM/4);
  tok_row_kernel<<<8, 256, 0, stream>>>(tgt_tokens, tokRow);

  // input projections (bias fused)
  gemm_mfma<0><<<dim3(16,32), 256, 0, stream>>>(xsrc, EDIM, eWih0b, EDIM, eb0,
                                                preZe, FOURH, EDIM, nullptr, nullptr, nullptr);
  gemm_mfma<0><<<dim3(16,32), 256, 0, stream>>>(ytgt, EDIM, dWih0b, EDIM+HDIM, db0,
                                                preZd, FOURH, EDIM, nullptr, nullptr, nullptr);

  // ---------------- encoder ----------------
  for (int t = 0; t < S_LEN; t++){
    int p = t & 1;
    float *h0p = h0s + p*ST, *c0p = c0s + p*ST, *h1p = h1s + p*ST, *c1p = c1s + p*ST;
    float *h0n = h0s + (1-p)*ST, *c0n = c0s + (1-p)*ST, *h1n = h1s + (1-p)*ST, *c1n = c1s + (1-p)*ST;
    enc_l0_kernel<<<256, 256, 0, stream>>>(preZe, eW_hh0, h0p, c0p, h0t, c0t, t);
    enc_l1_kernel<<<256, 256, 0, stream>>>(eW_ih1, eW_hh1, eb1, h0t, c0t, h1p, c1p, h0p, c0p,
                                           h0n, c0n, h1n, c1n, ench, encode_len, t);
  }
  // after 64 steps, final states are at parity 0 (t=63 wrote 1-(63&1)=0)

  // ---------------- decoder ----------------
  for (int t = 0; t < T_LEN; t++){
    int p = t & 1;
    float *h0p = h0s + p*ST, *c0p = c0s + p*ST, *h1p = h1s + p*ST, *c1p = c1s + p*ST;
    float *h0n = h0s + (1-p)*ST, *c0n = c0s + (1-p)*ST, *h1n = h1s + (1-p)*ST, *c1n = c1s + (1-p)*ST;
    float *htp = hts + p*ST, *htn = hts + (1-p)*ST;
    dec_l0_kernel<<<256, 256, 0, stream>>>(preZd, dW_ih0, dW_hh0, htp, h0p, c0p, h0t, c0t, t);
    dec_l1_kernel<<<256, 256, 0, stream>>>(dW_ih1, dW_hh1, db1, h0t, c0t, h1p, c1p,
                                           h0n, c0n, h1n, c1n, ytb);
    dec_attn_a<<<768, 256, 0, stream>>>(W_ht2tan, ytb, ench, tanv, scores);
    dec_attn_b<<<32, 256, 0, stream>>>(tanv, w_tan2pt, scores, encode_len, ench, ctb);
    dec_attn_c<<<256, 256, 0, stream>>>(W_ct2ht, ctb, ytb, htn, decoutb, t);
  }

  // ---------------- final projection + fused logsumexp ----------------
  gemm_mfma<1><<<dim3(16,250), 256, 0, stream>>>(decoutb, HDIM, Wfinb, HDIM, nullptr,
                                                 nullptr, 0, HDIM, rowSum, logitTgt, tokRow);
  loss_kernel<<<32, 64, 0, stream>>>(rowSum, logitTgt, tgt_tokens, out);
}